// Round 12
// baseline (225.783 us; speedup 1.0000x reference)
//
#include <hip/hip_runtime.h>
#include <stdint.h>

// DBSCAN, N=16384 points in R^3, eps=0.2, minPts=10.
//
// R12 (3 launches): R11's verified dataflow with hook0+jump+hook1+cc_final
// collapsed into ONE kernel via the last-block-done pattern (NOT grid.sync —
// R9 measured ~150us/sync; this is rocPRIM-lookback-style: each block
// releases with __threadfence (agent fence -> buffer_wbl2, flushes its XCD
// L2) + seq_cst agent atomicAdd(done); the block seeing prev==gridDim-1
// acquires (buffer_inv) and runs the single-block finale solo).
//   k_init       : deg=1, parent=i, counters=0
//   k_edges      : packed-triangular N^2 (i-tile 1024/IPT=4 x j-tile 128,
//                  1088 blocks, diagonal specialization) -> edges + degrees
//   k_hook_final : phase 1 (256 blocks x 1024): grid-stride classify all
//                  edges (core-core -> cclist + fire-and-forget atomicMin
//                  hook; mixed -> mbuf). Phase 2 (last block only): parent ->
//                  LDS, wavefront compress (replaces k_jump), contraction
//                  rounds DIRECTLY over cclist to exact fixpoint (replaces
//                  k_hook1), roots re-encoded in place as ENCB+rank, cores ->
//                  root code, borders take LDS atomicMin of neighbor codes,
//                  direct label write.
//
// Hard-won constraints (R2/R9/R10): no device-scope CAS retry loops; no
// grid.sync; no dependent pointer-chases in wide hot loops.
//
// Numerics replicate the reference EXACTLY in fp32 (absmax=0 in R1-R11):
//   sq  = (x*x + y*y) + z*z               (left-to-right)
//   dot = fma(z,z', fma(y,y', x*x'))      (BLAS k-ordered FMA chain)
//   d2  = (sq_i + sq_j) - 2.0f*dot ; adj = d2 < 0.04f

#define N_PTS   16384
#define BLOCK   256
#define IPT     4
#define ITILE   1024                    // IPT * BLOCK
#define JT      128
#define NTI     (N_PTS / ITILE)         // 16
#define NBLK    (4 * NTI * (NTI + 1))   // 1088 triangular tiles
#define EPS2    0.04f
#define MINPTS  10
#define ECAP    262144
#define CCAP    262144
#define MCAP    65536
#define BCAP    131072
#define LBUF    1024
#define GRID3   256                     // k_hook_final blocks
#define TPB3    1024                    // k_hook_final threads/block
#define CHUNK   (N_PTS / TPB3)          // 16
#define BIG     N_PTS                   // border sentinel in LDS parent
#define ENCB    16400                   // cluster-code base (> BIG)
#define HUGEV   (1 << 29)               // noise sentinel after re-encoding

__device__ __forceinline__ float sqsum(float x, float y, float z) {
    return __fadd_rn(__fadd_rn(__fmul_rn(x, x), __fmul_rn(y, y)), __fmul_rn(z, z));
}
__device__ __forceinline__ float dist2(float px, float py, float pz, float sqi, float4 q) {
    float dot = __fmaf_rn(pz, q.z, __fmaf_rn(py, q.y, __fmul_rn(px, q.x)));
    return __fsub_rn(__fadd_rn(sqi, q.w), __fmul_rn(2.0f, dot));
}
__device__ __forceinline__ int pload(const int* p) {
    return __hip_atomic_load(p, __ATOMIC_RELAXED, __HIP_MEMORY_SCOPE_AGENT);
}

// ---------------------------------------------------------------------------
__global__ void k_init(int* __restrict__ deg, int* __restrict__ parent,
                       int* __restrict__ cnts) {
    int i = blockIdx.x * BLOCK + threadIdx.x;
    deg[i] = 1;            // self-neighbor (d=0 < eps)
    parent[i] = i;
    if (i < 8) cnts[i] = 0;   // 0=gcnt 1=ccnt 2=mcnt 3=unused 4=done
}

// Packed triangular N^2: i-tile 1024, j-tile 128 (R7/R11 verbatim).
__global__ void k_edges(const float* __restrict__ pts,
                        uint32_t* __restrict__ edges, int* __restrict__ gcnt,
                        int* __restrict__ deg) {
    int b = blockIdx.x;
    float t = sqrtf((float)b + 1.0f);
    int bi = (int)((t - 1.0f) * 0.5f);
    while (4 * (bi + 1) * (bi + 2) <= b) ++bi;
    while (4 * bi * (bi + 1) > b) --bi;
    int jc = b - 4 * bi * (bi + 1);
    const int i0 = bi * ITILE, j0 = jc * JT;
    const bool diag = (jc >= 8 * bi);

    __shared__ float4 sj[JT];
    __shared__ int sdeg[JT];
    __shared__ uint32_t lbuf[LBUF];
    __shared__ int lcnt, lbase;
    const int tid = threadIdx.x;
    if (tid == 0) lcnt = 0;
    if (tid < JT) {
        int j = j0 + tid;
        float x = pts[3 * j], y = pts[3 * j + 1], z = pts[3 * j + 2];
        sj[tid] = make_float4(x, y, z, sqsum(x, y, z));
        sdeg[tid] = 0;
    }
    __syncthreads();
    float px[IPT], py[IPT], pz[IPT], sqi[IPT];
    int ii[IPT], cnt[IPT];
#pragma unroll
    for (int k = 0; k < IPT; ++k) {
        int i = i0 + k * BLOCK + tid;
        ii[k] = i;
        px[k] = pts[3 * i]; py[k] = pts[3 * i + 1]; pz[k] = pts[3 * i + 2];
        sqi[k] = sqsum(px[k], py[k], pz[k]);
        cnt[k] = 0;
    }
    if (!diag) {                                  // jg < i guaranteed
#pragma unroll 4
        for (int j = 0; j < JT; ++j) {
            float4 q = sj[j];
            int jg = j0 + j;
#pragma unroll
            for (int k = 0; k < IPT; ++k) {
                float d2 = dist2(px[k], py[k], pz[k], sqi[k], q);
                if (d2 < EPS2) {
                    int s = atomicAdd(&lcnt, 1);
                    if (s < LBUF) lbuf[s] = ((uint32_t)ii[k] << 14) | (uint32_t)jg;
                    ++cnt[k];
                    atomicAdd(&sdeg[j], 1);
                }
            }
        }
    } else {
#pragma unroll 4
        for (int j = 0; j < JT; ++j) {
            float4 q = sj[j];
            int jg = j0 + j;
#pragma unroll
            for (int k = 0; k < IPT; ++k) {
                float d2 = dist2(px[k], py[k], pz[k], sqi[k], q);
                if (d2 < EPS2 && jg < ii[k]) {
                    int s = atomicAdd(&lcnt, 1);
                    if (s < LBUF) lbuf[s] = ((uint32_t)ii[k] << 14) | (uint32_t)jg;
                    ++cnt[k];
                    atomicAdd(&sdeg[j], 1);
                }
            }
        }
    }
#pragma unroll
    for (int k = 0; k < IPT; ++k)
        if (cnt[k]) atomicAdd(&deg[ii[k]], cnt[k]);
    __syncthreads();
    if (tid < JT && sdeg[tid]) atomicAdd(&deg[j0 + tid], sdeg[tid]);
    if (tid == 0) {
        int n = min(lcnt, LBUF);
        lcnt = n;
        lbase = atomicAdd(gcnt, n);
    }
    __syncthreads();
    for (int t2 = tid; t2 < lcnt; t2 += BLOCK) {
        int s = lbase + t2;
        if (s < ECAP) edges[s] = lbuf[t2];
    }
}

// ---------------------------------------------------------------------------
// Phase 1 (all 256 blocks): classify edges + hook. Phase 2 (last block):
// the complete R11 finale (jump-compress + contraction over cclist + labels).
__global__ void __launch_bounds__(TPB3)
k_hook_final(const uint32_t* __restrict__ edges, const int* __restrict__ gcnt,
             const int* __restrict__ deg, int* __restrict__ parent_g,
             uint32_t* __restrict__ cclist, int* __restrict__ ccnt,
             uint32_t* __restrict__ mbuf, int* __restrict__ mcnt,
             int* __restrict__ done,
             uint32_t* __restrict__ bufA, uint32_t* __restrict__ bufB,
             float* __restrict__ out) {
    __shared__ int lpar[N_PTS];                    // 64 KB (finale only)
    __shared__ int s_nout, s_last;
    __shared__ int wsum[16];
    const int tid = threadIdx.x, lane = tid & 63, wv = tid >> 6;
    const uint64_t lane_lt = (1ull << lane) - 1;

    // ---- phase 1: grid-stride hook0 ----------------------------------------
    {
        const int n = min(pload(gcnt), ECAP);
        for (int e = blockIdx.x * TPB3 + tid; e < n; e += GRID3 * TPB3) {
            uint32_t p = edges[e];
            int i = (int)(p >> 14), j = (int)(p & (N_PTS - 1));
            bool ci = deg[i] >= MINPTS, cj = deg[j] >= MINPTS;
            bool cc = ci && cj, mx = ci != cj;
            if (cc) atomicMin(&parent_g[max(i, j)], min(i, j));  // fire-and-forget
            uint64_t m1 = __ballot(cc);
            if (m1) {
                int ldr = (int)__ffsll((unsigned long long)m1) - 1;
                int base = 0;
                if (lane == ldr) base = atomicAdd(ccnt, (int)__popcll(m1));
                base = __shfl(base, ldr);
                if (cc) {
                    int pos = base + (int)__popcll(m1 & lane_lt);
                    if (pos < CCAP) cclist[pos] = p;
                }
            }
            uint64_t m2 = __ballot(mx);
            if (m2) {
                int ldr = (int)__ffsll((unsigned long long)m2) - 1;
                int base = 0;
                if (lane == ldr) base = atomicAdd(mcnt, (int)__popcll(m2));
                base = __shfl(base, ldr);
                if (mx) {
                    uint32_t pk = ci ? (((uint32_t)i << 14) | (uint32_t)j)
                                     : (((uint32_t)j << 14) | (uint32_t)i); // core<<14|border
                    int pos = base + (int)__popcll(m2 & lane_lt);
                    if (pos < MCAP) mbuf[pos] = pk;
                }
            }
        }
    }
    // ---- last-block handoff (release: L2 writeback; acquire: invalidate) ---
    __syncthreads();
    if (tid == 0) {
        __threadfence();                            // agent release (buffer_wbl2)
        int prev = __hip_atomic_fetch_add(done, 1, __ATOMIC_SEQ_CST,
                                          __HIP_MEMORY_SCOPE_AGENT);
        s_last = (prev == GRID3 - 1) ? 1 : 0;
    }
    __syncthreads();
    if (!s_last) return;
    __threadfence();                                // agent acquire (buffer_inv)

    // ---- phase 2: finale (R11 k_cc_final, input = cclist) ------------------
#pragma unroll
    for (int k = 0; k < CHUNK; ++k) {
        int x = k * TPB3 + tid;                     // coalesced
        lpar[x] = (deg[x] >= MINPTS) ? pload(&parent_g[x]) : BIG;
    }
    __syncthreads();
    // initial compress: wavefront chase, 16 independent streams per thread
    {
        int v[CHUNK];
#pragma unroll
        for (int k = 0; k < CHUNK; ++k) v[k] = lpar[k * TPB3 + tid];
        bool any = true;
        while (any) {
            any = false;
#pragma unroll
            for (int k = 0; k < CHUNK; ++k) {
                if (v[k] < BIG) {
                    int q = lpar[v[k]];
                    if (q != v[k]) { v[k] = q; any = true; }
                }
            }
        }
#pragma unroll
        for (int k = 0; k < CHUNK; ++k)
            if (v[k] < BIG) lpar[k * TPB3 + tid] = v[k];
    }
    __syncthreads();

    // contraction rounds to exact fixpoint; round 0 scans the full cclist
    int n_in = min(pload(ccnt), CCAP);
    const uint32_t* cur = cclist;
    for (int r = 0; r < 24; ++r) {
        uint32_t* nxt = (r & 1) ? bufB : bufA;
        if (tid == 0) s_nout = 0;
        __syncthreads();
        const int n4 = (n_in + 3) & ~3;
        for (int bb = tid * 4; bb < n4; bb += TPB3 * 4) {
            uint4 pk = *(const uint4*)(cur + bb);
#pragma unroll
            for (int k = 0; k < 4; ++k) {
                uint32_t p = (k == 0) ? pk.x : (k == 1) ? pk.y : (k == 2) ? pk.z : pk.w;
                bool valid = (bb + k) < n_in;
                int ri = 0, rj = 0;
                if (valid) {
                    ri = lpar[(int)(p >> 14)];
                    rj = lpar[(int)(p & (N_PTS - 1))];
                }
                bool live = valid && (ri != rj);
                int lo = min(ri, rj), hi = max(ri, rj);
                if (live) atomicMin(&lpar[hi], lo);          // LDS fire-and-forget
                uint64_t m = __ballot(live);
                if (m) {
                    int ldr = (int)__ffsll((unsigned long long)m) - 1;
                    int base = 0;
                    if (lane == ldr) base = atomicAdd(&s_nout, (int)__popcll(m));
                    base = __shfl(base, ldr);
                    if (live) {
                        int pos = base + (int)__popcll(m & lane_lt);
                        if (pos < BCAP) nxt[pos] = ((uint32_t)hi << 14) | (uint32_t)lo;
                    }
                }
            }
        }
        __syncthreads();
        int v[CHUNK];
#pragma unroll
        for (int k = 0; k < CHUNK; ++k) v[k] = lpar[k * TPB3 + tid];
        bool any = true;
        while (any) {
            any = false;
#pragma unroll
            for (int k = 0; k < CHUNK; ++k) {
                if (v[k] < BIG) {
                    int q = lpar[v[k]];
                    if (q != v[k]) { v[k] = q; any = true; }
                }
            }
        }
#pragma unroll
        for (int k = 0; k < CHUNK; ++k)
            if (v[k] < BIG) lpar[k * TPB3 + tid] = v[k];
        __syncthreads();
        if (s_nout == 0) break;                     // uniform
        n_in = min(s_nout, BCAP);
        cur = nxt;
    }

    // D1: rank roots ascending; re-encode root slots in place as ENCB+rank
    const int bn = tid * CHUNK;
    int fl[CHUNK]; int s = 0;
#pragma unroll
    for (int k = 0; k < CHUNK; ++k) {
        fl[k] = (lpar[bn + k] == bn + k) ? 1 : 0;   // borders hold BIG != index
        s += fl[k];
    }
    int incl = s;
#pragma unroll
    for (int d = 1; d < 64; d <<= 1) { int t = __shfl_up(incl, d, 64); if (lane >= d) incl += t; }
    if (lane == 63) wsum[wv] = incl;
    __syncthreads();
    int wbase = 0;
    for (int w = 0; w < wv; ++w) wbase += wsum[w];
    int c = wbase + incl - s;
#pragma unroll
    for (int k = 0; k < CHUNK; ++k)
        if (fl[k]) lpar[bn + k] = ENCB + (c++);
    __syncthreads();
    // D2: non-root cores -> root's code; borders -> HUGE sentinel
#pragma unroll
    for (int k = 0; k < CHUNK; ++k) {
        int x = k * TPB3 + tid;
        int p = lpar[x];
        if (p < BIG) lpar[x] = lpar[p];             // root slots stable (>= ENCB)
        else if (p == BIG) lpar[x] = HUGEV;
    }
    __syncthreads();
    // C: border labels = min neighbor-cluster code (rank monotone in root)
    int nm = min(pload(mcnt), MCAP);
    for (int e = tid; e < nm; e += TPB3) {
        uint32_t p = mbuf[e];
        int cc = (int)(p >> 14), bb = (int)(p & (N_PTS - 1));
        atomicMin(&lpar[bb], lpar[cc]);             // LDS
    }
    __syncthreads();
    // E: labels
#pragma unroll
    for (int k = 0; k < CHUNK; ++k) {
        int x = k * TPB3 + tid;                     // coalesced store
        int v = lpar[x];
        out[x] = (v < HUGEV) ? (float)(v - ENCB) : -1.0f;
    }
}

// ---------------------------------------------------------------------------
extern "C" void kernel_launch(void* const* d_in, const int* in_sizes, int n_in,
                              void* d_out, int out_size, void* d_ws, size_t ws_size,
                              hipStream_t stream) {
    (void)in_sizes; (void)n_in; (void)out_size; (void)ws_size;
    const float* pts = (const float*)d_in[0];
    float* out = (float*)d_out;

    // ws layout (words; all list offsets multiples of 16 -> uint4-safe)
    int* ib = (int*)d_ws;
    int*      deg    = ib;                         // 16384
    int*      parent = deg + N_PTS;                // 16384
    int*      cnts   = parent + N_PTS;             // 64
    int*      gcnt = cnts + 0, *ccnt = cnts + 1, *mcnt = cnts + 2, *done = cnts + 4;
    uint32_t* edges  = (uint32_t*)(cnts + 64);     // 262144
    uint32_t* cclist = edges + ECAP;               // 262144
    uint32_t* mbuf   = cclist + CCAP;              // 65536
    uint32_t* bufA   = mbuf + MCAP;                // 131072
    uint32_t* bufB   = bufA + BCAP;                // 131072  (~3.4 MB total)

    dim3 blk(BLOCK);
    k_init      <<<dim3(N_PTS / BLOCK), blk, 0, stream>>>(deg, parent, cnts);
    k_edges     <<<dim3(NBLK), blk, 0, stream>>>(pts, edges, gcnt, deg);
    k_hook_final<<<dim3(GRID3), dim3(TPB3), 0, stream>>>(edges, gcnt, deg, parent,
                                                         cclist, ccnt, mbuf, mcnt,
                                                         done, bufA, bufB, out);
}